// Round 4
// baseline (640.399 us; speedup 1.0000x reference)
//
#include <hip/hip_runtime.h>

// Problem constants (reference: N=65536, D=512, S=262144)
#define NROWS 65536
#define DCOLS 512
#define D4    128   // float4 per row

// Native 16B vector type usable with __builtin_nontemporal_store
typedef float f32x4 __attribute__((ext_vector_type(4)));

// ---------------------------------------------------------------------------
// Kernel 1: inclusive prefix sum of feeds_repeat_times (N=65536) into cum[].
// Single block: 1024 threads x 64 elements each.
// ---------------------------------------------------------------------------
__global__ __launch_bounds__(1024) void scan_kernel(const int* __restrict__ rep,
                                                    int* __restrict__ cum) {
    __shared__ int sdata[1024];
    const int t = threadIdx.x;
    const int base = t * 64;

    int4 v[16];
    const int4* rep4 = (const int4*)(rep + base);
#pragma unroll
    for (int k = 0; k < 16; ++k) v[k] = rep4[k];

    int partial = 0;
#pragma unroll
    for (int k = 0; k < 16; ++k) partial += v[k].x + v[k].y + v[k].z + v[k].w;

    sdata[t] = partial;
    __syncthreads();
    for (int off = 1; off < 1024; off <<= 1) {
        int add = (t >= off) ? sdata[t - off] : 0;
        __syncthreads();
        sdata[t] += add;
        __syncthreads();
    }
    int running = sdata[t] - partial;  // exclusive prefix of this thread's chunk

    int4* cum4 = (int4*)(cum + base);
#pragma unroll
    for (int k = 0; k < 16; ++k) {
        int4 x;
        running += v[k].x; x.x = running;
        running += v[k].y; x.y = running;
        running += v[k].z; x.z = running;
        running += v[k].w; x.w = running;
        cum4[k] = x;
    }
}

// ---------------------------------------------------------------------------
// Kernel 2: build idx[j] = source row for every valid output row j.
// One thread per source row; writes r_i ints to [cum[i]-r_i, cum[i]).
// ---------------------------------------------------------------------------
__global__ __launch_bounds__(256) void build_idx_kernel(const int* __restrict__ rep,
                                                        const int* __restrict__ cum,
                                                        int* __restrict__ idx,
                                                        int S) {
    const int i = blockIdx.x * blockDim.x + threadIdx.x;
    if (i >= NROWS) return;
    const int end   = cum[i];
    const int r     = rep[i];
    const int start = end - r;
    if (r == 0 || start >= S) return;
    const int stop = end < S ? end : S;
    for (int j = start; j < stop; ++j) idx[j] = i;
}

// ---------------------------------------------------------------------------
// Kernel 3: gather, persistent-wave version. 16384 waves; wave w owns 16
// contiguous output rows [w*16, w*16+16). Per row: wave-uniform idx[row]
// broadcast load (L1), 2KB row copy (2 x float4/lane), nontemporal stores.
// Source row kept in registers and reused when consecutive rows share it
// (idx is monotone; avg repeat 3.5 -> ~3.5x fewer feeds loads).
// Rows >= total get zeros (d_out is poisoned 0xAA every call).
// ---------------------------------------------------------------------------
#define ROWS_PER_WAVE 16
__global__ __launch_bounds__(256) void gather_kernel(const f32x4* __restrict__ feeds,
                                                     const int* __restrict__ idx,
                                                     const int* __restrict__ cum,
                                                     f32x4* __restrict__ out,
                                                     int S) {
    const int wave = (int)((blockIdx.x * blockDim.x + threadIdx.x) >> 6);
    const int lane = threadIdx.x & 63;
    const int rowBeg = wave * ROWS_PER_WAVE;
    if (rowBeg >= S) return;

    const int total = cum[NROWS - 1];

    int prev = -1;
    f32x4 a = (f32x4)0.f;
    f32x4 b = (f32x4)0.f;

#pragma unroll 4
    for (int k = 0; k < ROWS_PER_WAVE; ++k) {
        const int j = rowBeg + k;
        f32x4 oa = (f32x4)0.f, ob = (f32x4)0.f;
        if (j < total) {
            const int si = idx[j];             // wave-uniform broadcast
            if (si != prev) {
                const f32x4* src = feeds + (long long)si * D4;
                a = src[lane];
                b = src[lane + 64];
                prev = si;
            }
            oa = a; ob = b;
        }
        f32x4* dst = out + (long long)j * D4;
        __builtin_nontemporal_store(oa, dst + lane);
        __builtin_nontemporal_store(ob, dst + lane + 64);
    }
}

extern "C" void kernel_launch(void* const* d_in, const int* in_sizes, int n_in,
                              void* d_out, int out_size, void* d_ws, size_t ws_size,
                              hipStream_t stream) {
    const float* feeds = (const float*)d_in[0];
    const int*   rep   = (const int*)d_in[1];
    const int S = out_size / DCOLS;  // 262144

    int* cum = (int*)d_ws;            // 65536 ints = 256 KB
    int* idx = (int*)d_ws + NROWS;    // S ints = 1 MiB

    scan_kernel<<<1, 1024, 0, stream>>>(rep, cum);
    build_idx_kernel<<<NROWS / 256, 256, 0, stream>>>(rep, cum, idx, S);
    // 16384 waves x 16 rows = 262144 rows; 4096 blocks x 256 threads.
    const int waves = (S + ROWS_PER_WAVE - 1) / ROWS_PER_WAVE;
    const int blocks = (waves * 64) / 256;
    gather_kernel<<<blocks, 256, 0, stream>>>((const f32x4*)feeds, idx, cum,
                                              (f32x4*)d_out, S);
}